// Round 8
// baseline (165.475 us; speedup 1.0000x reference)
//
#include <hip/hip_runtime.h>
#include <hip/hip_bf16.h>
#include <cstddef>
#include <cstdint>

// Problem dims
constexpr int Bv = 128;   // batch
constexpr int Sv = 256;   // src len
constexpr int Hv = 1024;  // hidden
constexpr int Ev = 512;   // embed
constexpr int Vv = 32000; // vocab

typedef __attribute__((ext_vector_type(4))) float f32x4;
typedef __attribute__((ext_vector_type(8))) short short8;

// f32x4 -> 4 packed bf16 (RNE), via v_cvt_pk_bf16_f32.
__device__ __forceinline__ uint2 cvt4(float4 v) {
  union { __hip_bfloat162 b; unsigned u; } lo, hi;
  lo.b = __float22bfloat162_rn(float2{v.x, v.y});
  hi.b = __float22bfloat162_rn(float2{v.z, v.w});
  uint2 r;
  r.x = lo.u;
  r.y = hi.u;
  return r;
}
__device__ __forceinline__ unsigned short cvt1(float x) {
  union { __hip_bfloat16 b; unsigned short u; } c;
  c.b = __float2bfloat16(x);
  return c.u;
}

// ---------------------------------------------------------------------------
// MFMA GEMM with split-K partials:
//   Cp[z][m,n] = sum_{k in split z} A[m,k]*W[n,k]  (+bias on z==0)
// A = A1 (k<K1, optionally gathered emb rows) then A2. W row-major [N,K]
// unless WTR (W1 is [K,N], transposed during LDS staging; needs BN==32).
// BK: K-tile per iteration. LSWZ: 1D-grid XCD-aware mapping where the two
// m-blocks sharing a W n-tile differ by exactly 8 in bid -> same XCD L2.
// Partial z written at C + z*gridDim.y*BM*ldc. Consumers sum partials.
// ---------------------------------------------------------------------------
template <int BM, int BN, int BK, int SPLIT, int WTR, int GATHER, int LSWZ,
          int MINW>
__global__ __launch_bounds__(256, MINW) void gemm_mfma(
    const int* __restrict__ ids,
    const float* __restrict__ A1, int lda1, int K1,
    const float* __restrict__ A2, int lda2, int K2,
    const float* __restrict__ W1, int ldw1,
    const float* __restrict__ W2, int ldw2,
    const float* __restrict__ bias1, const float* __restrict__ bias2,
    float* __restrict__ C, int ldc, int N) {
  constexpr int LP = BK + 8;       // LDS row pitch in bf16 (+8 pad)
  constexpr int KQ = BK / 4;       // float4 chunks per row
  constexpr int KSUB = BK / 32;    // MFMA K-subtiles per iteration
  constexpr int WAVES_N = (BN >= 64) ? 2 : 1;
  constexpr int WAVES_M = 4 / WAVES_N;
  constexpr int WM = BM / WAVES_M;
  constexpr int FM = WM / 16;
  constexpr int FN = 2;  // WN = 32
  constexpr int ACH = (BM * BK) / (4 * 256);
  constexpr int WCH = (BN * BK) / (4 * 256);
  constexpr int WVN = WTR ? (BK * 8 / 256) : WCH;

  __shared__ unsigned short Al[BM * LP];
  __shared__ unsigned short Wl[BN * LP];

  const int tid = threadIdx.x;
  const int wid = tid >> 6, lane = tid & 63;
  int nBlock, mBlock;
  if (LSWZ) {
    // 16 consecutive bids = 8 n-tiles x 2 m-tiles; (w) and (w+8) share the
    // n-tile and land on the same XCD (bid diff == 8 == NXCD).
    int bid = blockIdx.x;
    int g = bid >> 4, w = bid & 15;
    int nIdx = g * 8 + (w & 7);
    int mIdx = w >> 3;
    if (nIdx * BN >= N) return;
    nBlock = nIdx * BN;
    mBlock = mIdx * BM;
  } else {
    nBlock = blockIdx.x * BN;
    mBlock = blockIdx.y * BM;
  }
  const int z = blockIdx.z;
  int wm, wn;
  if (WAVES_N == 2) { wm = (wid >> 1) * WM; wn = (wid & 1) * 32; }
  else              { wm = wid * WM;        wn = 0; }

  float4 av[ACH], wv[WVN];

  auto load_tile = [&](int kg) {
    const bool seg1 = kg < K1;
    const float* Wseg = seg1 ? W1 : W2;
    const int ldw = seg1 ? ldw1 : ldw2;
    const int kloc = seg1 ? kg : kg - K1;
#pragma unroll
    for (int i = 0; i < ACH; i++) {
      int c = tid + i * 256;
      int m = c / KQ, kq = (c % KQ) * 4;
      const float* arow;
      if (seg1) {
        if (GATHER) arow = A1 + (size_t)ids[mBlock + m] * lda1;
        else        arow = A1 + (size_t)(mBlock + m) * lda1;
      } else {
        arow = A2 + (size_t)(mBlock + m) * lda2;
      }
      av[i] = *(const float4*)(arow + kloc + kq);
    }
    if (WTR) {
#pragma unroll
      for (int i = 0; i < WVN; i++) {
        int c = tid + i * 256;           // BK k-rows x 8 n-quads
        int row = c >> 3, colq = c & 7;
        wv[i] = *(const float4*)(Wseg + (size_t)(kloc + row) * ldw + nBlock + colq * 4);
      }
    } else {
#pragma unroll
      for (int i = 0; i < WCH; i++) {
        int c = tid + i * 256;
        int n = c / KQ, kq = (c % KQ) * 4;
        wv[i] = *(const float4*)(Wseg + (size_t)(nBlock + n) * ldw + kloc + kq);
      }
    }
  };

  const int KT = K1 + K2;
  const int KS = KT / SPLIT;          // per-split K (multiple of BK; segment-aligned)
  const int kbeg = z * KS;
  const int NS = KS / BK;
  load_tile(kbeg);
  f32x4 acc[FM][FN] = {};

  for (int step = 0; step < NS; ++step) {
    __syncthreads();  // previous iteration's fragment reads done
    // commit regs -> LDS (f32 -> bf16, packed 8B stores)
#pragma unroll
    for (int i = 0; i < ACH; i++) {
      int c = tid + i * 256;
      int m = c / KQ, kq = (c % KQ) * 4;
      *(uint2*)&Al[m * LP + kq] = cvt4(av[i]);
    }
    if (WTR) {
#pragma unroll
      for (int i = 0; i < WVN; i++) {
        int c = tid + i * 256;
        int row = c >> 3, colq = c & 7;
        Wl[(colq * 4 + 0) * LP + row] = cvt1(wv[i].x);
        Wl[(colq * 4 + 1) * LP + row] = cvt1(wv[i].y);
        Wl[(colq * 4 + 2) * LP + row] = cvt1(wv[i].z);
        Wl[(colq * 4 + 3) * LP + row] = cvt1(wv[i].w);
      }
    } else {
#pragma unroll
      for (int i = 0; i < WCH; i++) {
        int c = tid + i * 256;
        int n = c / KQ, kq = (c % KQ) * 4;
        *(uint2*)&Wl[n * LP + kq] = cvt4(wv[i]);
      }
    }
    __syncthreads();

    if (step + 1 < NS) load_tile(kbeg + (step + 1) * BK);  // prefetch

    const int klane = (lane >> 4) << 3;
    const int r = lane & 15;
    short8 af[KSUB][FM], wf[KSUB][FN];
#pragma unroll
    for (int ks = 0; ks < KSUB; ks++) {
#pragma unroll
      for (int f = 0; f < FM; f++)
        af[ks][f] = *(const short8*)&Al[(wm + f * 16 + r) * LP + ks * 32 + klane];
#pragma unroll
      for (int f = 0; f < FN; f++)
        wf[ks][f] = *(const short8*)&Wl[(wn + f * 16 + r) * LP + ks * 32 + klane];
    }
#pragma unroll
    for (int ks = 0; ks < KSUB; ks++)
#pragma unroll
      for (int fm = 0; fm < FM; fm++)
#pragma unroll
        for (int fn = 0; fn < FN; fn++)
          acc[fm][fn] = __builtin_amdgcn_mfma_f32_16x16x32_bf16(
              af[ks][fm], wf[ks][fn], acc[fm][fn], 0, 0, 0);
  }

  // Epilogue. D layout: col = lane&15, row = (lane>>4)*4 + j
  float* Cp = C + (size_t)z * gridDim.y * BM * ldc;
  const int col = lane & 15, rb = (lane >> 4) << 2;
#pragma unroll
  for (int fn = 0; fn < FN; fn++) {
    int n = nBlock + wn + fn * 16 + col;
    float bsum = 0.f;
    if (z == 0) {
      if (bias1) bsum += bias1[n];
      if (bias2) bsum += bias2[n];
    }
#pragma unroll
    for (int fm = 0; fm < FM; fm++) {
#pragma unroll
      for (int j = 0; j < 4; j++) {
        int m = mBlock + wm + fm * 16 + rb + j;
        Cp[(size_t)m * ldc + n] = acc[fm][fn][j] + bsum;
      }
    }
  }
}

// ---------------------------------------------------------------------------
template <int P>
__global__ void lstm_pw(const float* __restrict__ Gp,
                        const float* __restrict__ c_prev,
                        float* __restrict__ h_out,
                        float* __restrict__ c_out) {
  int i4 = blockIdx.x * 256 + threadIdx.x;  // 32768 float4 slots (B*H/4)
  int b = i4 >> 8, j4 = i4 & 255;
  float4 gi{}, gf{}, gg{}, go{};
#pragma unroll
  for (int p = 0; p < P; p++) {
    const float4* g = (const float4*)(Gp + (size_t)p * Bv * 4 * Hv + (size_t)b * 4096);
    float4 a = g[j4], bb = g[256 + j4], c = g[512 + j4], d = g[768 + j4];
    gi.x += a.x; gi.y += a.y; gi.z += a.z; gi.w += a.w;
    gf.x += bb.x; gf.y += bb.y; gf.z += bb.z; gf.w += bb.w;
    gg.x += c.x; gg.y += c.y; gg.z += c.z; gg.w += c.w;
    go.x += d.x; go.y += d.y; go.z += d.z; go.w += d.w;
  }
  float4 c4 = ((const float4*)c_prev)[i4];
  float4 h4, cn4;
  float* gip = &gi.x; float* gfp = &gf.x; float* ggp = &gg.x; float* gop = &go.x;
  float* cp = &c4.x; float* hp = &h4.x; float* cnp = &cn4.x;
#pragma unroll
  for (int u = 0; u < 4; u++) {
    float si = 1.f / (1.f + expf(-gip[u]));
    float sf = 1.f / (1.f + expf(-gfp[u]));
    float so = 1.f / (1.f + expf(-gop[u]));
    float cn = sf * cp[u] + si * tanhf(ggp[u]);
    hp[u] = so * tanhf(cn);
    cnp[u] = cn;
  }
  ((float4*)h_out)[i4] = h4;
  ((float4*)c_out)[i4] = cn4;
}

// ---------------------------------------------------------------------------
// scores[b,s] = <enc[s,b,:], q[b,:]>, q = sum of 4 split-K partials staged in
// LDS once per block. 16 s-rows per block (amortizes q staging 4x vs 4 rows).
// attn_b term cancels in softmax.
__global__ void scores_k(const float* __restrict__ enc,
                         const float* __restrict__ qp,
                         float* __restrict__ sc) {
  int blk = blockIdx.x;           // B * S/16 = 2048
  int b = blk >> 4, s16 = blk & 15;
  int t = threadIdx.x;
  __shared__ float qs[1024];
  {
    const float4* q0 = (const float4*)(qp + (size_t)b * Hv);
    const float4* q1 = (const float4*)(qp + 1 * Bv * Hv + (size_t)b * Hv);
    const float4* q2 = (const float4*)(qp + 2 * Bv * Hv + (size_t)b * Hv);
    const float4* q3 = (const float4*)(qp + 3 * Bv * Hv + (size_t)b * Hv);
    float4 a = q0[t], bq = q1[t], c = q2[t], d = q3[t];
    float4 s;
    s.x = a.x + bq.x + c.x + d.x; s.y = a.y + bq.y + c.y + d.y;
    s.z = a.z + bq.z + c.z + d.z; s.w = a.w + bq.w + c.w + d.w;
    ((float4*)qs)[t] = s;
  }
  __syncthreads();
  int wid = t >> 6, lane = t & 63;
  int s0 = s16 * 16 + wid * 4;    // each wave owns 4 consecutive s
  const float4* q4 = (const float4*)qs;
  float sum[4] = {0.f, 0.f, 0.f, 0.f};
#pragma unroll
  for (int j = 0; j < 4; j++) {
    int idx = lane + j * 64;
    float4 qq = q4[idx];
#pragma unroll
    for (int i = 0; i < 4; i++) {
      float4 e = *(const float4*)(enc + ((size_t)(s0 + i) * Bv + b) * Hv + idx * 4);
      sum[i] += e.x * qq.x + e.y * qq.y + e.z * qq.z + e.w * qq.w;
    }
  }
#pragma unroll
  for (int i = 0; i < 4; i++)
#pragma unroll
    for (int o = 32; o; o >>= 1) sum[i] += __shfl_xor(sum[i], o);
  if (lane == 0)
    *(float4*)(sc + (size_t)b * Sv + s0) =
        make_float4(sum[0], sum[1], sum[2], sum[3]);
}

// ---------------------------------------------------------------------------
// Per block (b, h-quarter): softmax over sc[b,:] (recomputed redundantly,
// cheap), then ctx[b, hc:hc+256] = sum_s attn[s]*enc[s,b,hc:hc+256].
// Lane owns a float4 of h; the 4 waves split the s-range; LDS reduce.
__global__ void context_k(const float* __restrict__ sc_in,
                          const float* __restrict__ enc,
                          float* __restrict__ ctx) {
  int blk = blockIdx.x;                 // B * 4 = 512
  int b = blk >> 2, hc = (blk & 3) * 256;
  int t = threadIdx.x, lane = t & 63, wid = t >> 6;
  __shared__ float a[256];
  __shared__ float redm[4], reds[4];
  float v = sc_in[(size_t)b * Sv + t];
  float m = v;
#pragma unroll
  for (int o = 32; o; o >>= 1) m = fmaxf(m, __shfl_xor(m, o));
  if (lane == 0) redm[t >> 6] = m;
  __syncthreads();
  m = fmaxf(fmaxf(redm[0], redm[1]), fmaxf(redm[2], redm[3]));
  float e = expf(v - m);
  float ssum = e;
#pragma unroll
  for (int o = 32; o; o >>= 1) ssum += __shfl_xor(ssum, o);
  if (lane == 0) reds[t >> 6] = ssum;
  __syncthreads();
  ssum = (reds[0] + reds[1]) + (reds[2] + reds[3]);
  a[t] = e / ssum;
  __syncthreads();

  // each wave accumulates its 64-s slice; lane covers h = hc+lane*4..+3
  float4 acc = make_float4(0.f, 0.f, 0.f, 0.f);
  const float* ebase = enc + (size_t)b * Hv + hc + lane * 4;
#pragma unroll 8
  for (int s = wid * 64; s < wid * 64 + 64; s++) {
    float4 e = *(const float4*)(ebase + (size_t)s * Bv * Hv);
    float w = a[s];
    acc.x += w * e.x; acc.y += w * e.y; acc.z += w * e.z; acc.w += w * e.w;
  }
  __shared__ float4 part[4][64];
  part[wid][lane] = acc;
  __syncthreads();
  if (wid == 0) {
    float4 p0 = part[0][lane], p1 = part[1][lane];
    float4 p2 = part[2][lane], p3 = part[3][lane];
    float4 r;
    r.x = (p0.x + p1.x) + (p2.x + p3.x);
    r.y = (p0.y + p1.y) + (p2.y + p3.y);
    r.z = (p0.z + p1.z) + (p2.z + p3.z);
    r.w = (p0.w + p1.w) + (p2.w + p3.w);
    *(float4*)(ctx + (size_t)b * Hv + hc + lane * 4) = r;
  }
}

// ---------------------------------------------------------------------------
__global__ void finish_cat(const float* __restrict__ catp,
                           float* __restrict__ cat) {
  int i4 = blockIdx.x * 256 + threadIdx.x;  // 32768 float4 slots
  constexpr int ST = Bv * Hv / 4;
  const float4* p = (const float4*)catp;
  float4 a = p[i4], b = p[ST + i4], c = p[2 * ST + i4], d = p[3 * ST + i4];
  float4 r;
  r.x = tanhf(a.x + b.x + c.x + d.x);
  r.y = tanhf(a.y + b.y + c.y + d.y);
  r.z = tanhf(a.z + b.z + c.z + d.z);
  r.w = tanhf(a.w + b.w + c.w + d.w);
  ((float4*)cat)[i4] = r;
}

// ---------------------------------------------------------------------------
extern "C" void kernel_launch(void* const* d_in, const int* in_sizes, int n_in,
                              void* d_out, int out_size, void* d_ws,
                              size_t ws_size, hipStream_t stream) {
  const int*   ids      = (const int*)d_in[0];
  const float* h0       = (const float*)d_in[1];
  const float* c0       = (const float*)d_in[2];
  const float* enc      = (const float*)d_in[3];
  const float* emb      = (const float*)d_in[4];
  const float* w_ih0    = (const float*)d_in[5];
  const float* w_hh0    = (const float*)d_in[6];
  const float* b_ih0    = (const float*)d_in[7];
  const float* b_hh0    = (const float*)d_in[8];
  const float* w_ih1    = (const float*)d_in[9];
  const float* w_hh1    = (const float*)d_in[10];
  const float* b_ih1    = (const float*)d_in[11];
  const float* b_hh1    = (const float*)d_in[12];
  const float* attn_w   = (const float*)d_in[13];
  const float* attn_b   = (const float*)d_in[14];  // cancels in softmax
  const float* concat_w = (const float*)d_in[15];
  const float* concat_b = (const float*)d_in[16];
  const float* out_w    = (const float*)d_in[17];
  const float* out_b    = (const float*)d_in[18];
  (void)attn_b;

  float* logits = (float*)d_out;                  // [128, 32000]
  float* hout   = logits + (size_t)Bv * Vv;       // [2, 128, 1024]
  float* cout   = hout + 2 * Bv * Hv;             // [2, 128, 1024]

  float* ws   = (float*)d_ws;
  float* G0p  = ws;                       // 3 * 524288
  float* G1p  = G0p + 3 * 524288;         // 4 * 524288
  float* qp   = G1p + 4 * (size_t)524288; // 4 * 131072
  float* catp = qp + 4 * 131072;          // 4 * 131072
  float* cat  = catp + 4 * 131072;        // 131072
  float* ctx  = cat + 131072;             // 131072
  float* sc   = ctx + 131072;             // 32768

  const float* h_b = hout + Bv * Hv;  // layer-1 h (rnn_out)

  // 1. LSTM layer 0 gates: K = 512(emb,gathered) + 1024(h0), 3-way split-K
  gemm_mfma<64, 32, 64, 3, 0, 1, 0, 4><<<dim3(128, 2, 3), 256, 0, stream>>>(
      ids, emb, Ev, Ev, h0, Hv, Hv, w_ih0, Ev, w_hh0, Hv, b_ih0, b_hh0,
      G0p, 4 * Hv, 4 * Hv);
  // 2. LSTM layer 0 pointwise (sums 3 partials); h -> hout[0]
  lstm_pw<3><<<128, 256, 0, stream>>>(G0p, c0, hout, cout);
  // 3. LSTM layer 1 gates: K = 1024(h_layer0) + 1024(h0[1]), 4-way split-K
  gemm_mfma<64, 32, 64, 4, 0, 0, 0, 4><<<dim3(128, 2, 4), 256, 0, stream>>>(
      nullptr, hout, Hv, Hv, h0 + Bv * Hv, Hv, Hv, w_ih1, Hv, w_hh1, Hv,
      b_ih1, b_hh1, G1p, 4 * Hv, 4 * Hv);
  // 4. LSTM layer 1 pointwise (sums 4 partials)
  lstm_pw<4><<<128, 256, 0, stream>>>(G1p, c0 + Bv * Hv, hout + Bv * Hv,
                                      cout + Bv * Hv);
  // 5. q = rnn @ attn_w (transposed in staging), 4-way split-K
  gemm_mfma<64, 32, 64, 4, 1, 0, 0, 4><<<dim3(32, 2, 4), 256, 0, stream>>>(
      nullptr, h_b, Hv, Hv, nullptr, 0, 0, attn_w, Hv,
      nullptr, 0, nullptr, nullptr, qp, Hv, Hv);
  // 6. scores (16 s-rows per block; q partials summed via LDS once)
  scores_k<<<2048, 256, 0, stream>>>(enc, qp, sc);
  // 7. softmax (redundant per block) + context, float4 streams
  context_k<<<512, 256, 0, stream>>>(sc, enc, ctx);
  // 8. concat gates: K = 1024(rnn) + 1024(ctx), 4-way split-K
  gemm_mfma<64, 32, 64, 4, 0, 0, 0, 4><<<dim3(32, 2, 4), 256, 0, stream>>>(
      nullptr, h_b, Hv, Hv, ctx, Hv, Hv, concat_w, 2 * Hv,
      concat_w + Hv, 2 * Hv, concat_b, nullptr, catp, Hv, Hv);
  // 9. cat = tanh(sum of partials)
  finish_cat<<<128, 256, 0, stream>>>(catp, cat);
  // 10. logits: BM=64/BN=64/BK=64, XCD-aware 1D grid (1008 blocks, 8 idle):
  //     m-block pairs sharing a W n-tile differ by 8 in bid -> same XCD L2.
  gemm_mfma<64, 64, 64, 1, 0, 0, 1, 4><<<dim3(1008, 1, 1), 256, 0, stream>>>(
      nullptr, cat, Hv, Hv, nullptr, 0, 0, out_w, Hv, nullptr, 0,
      out_b, nullptr, logits, Vv, Vv);
}

// Round 9
// 154.843 us; speedup vs baseline: 1.0687x; 1.0687x over previous
//
#include <hip/hip_runtime.h>
#include <hip/hip_bf16.h>
#include <cstddef>
#include <cstdint>

// Problem dims
constexpr int Bv = 128;   // batch
constexpr int Sv = 256;   // src len
constexpr int Hv = 1024;  // hidden
constexpr int Ev = 512;   // embed
constexpr int Vv = 32000; // vocab

typedef __attribute__((ext_vector_type(4))) float f32x4;
typedef __attribute__((ext_vector_type(8))) short short8;

// f32x4 -> 4 packed bf16 (RNE), via v_cvt_pk_bf16_f32.
__device__ __forceinline__ uint2 cvt4(float4 v) {
  union { __hip_bfloat162 b; unsigned u; } lo, hi;
  lo.b = __float22bfloat162_rn(float2{v.x, v.y});
  hi.b = __float22bfloat162_rn(float2{v.z, v.w});
  uint2 r;
  r.x = lo.u;
  r.y = hi.u;
  return r;
}
__device__ __forceinline__ unsigned short cvt1(float x) {
  union { __hip_bfloat16 b; unsigned short u; } c;
  c.b = __float2bfloat16(x);
  return c.u;
}

// ---------------------------------------------------------------------------
// MFMA GEMM with split-K partials:
//   Cp[z][m,n] = sum_{k in split z} A[m,k]*W[n,k]  (+bias on z==0)
// A = A1 (k<K1, optionally gathered emb rows) then A2. W row-major [N,K]
// unless WTR (W1 is [K,N], transposed during LDS staging; needs BN==32).
// BK: K-tile per iteration. Bigger BK = more loads in flight per wave.
// Partial z written at C + z*gridDim.y*BM*ldc. Consumers sum partials.
// ---------------------------------------------------------------------------
template <int BM, int BN, int BK, int SPLIT, int WTR, int GATHER, int MINW>
__global__ __launch_bounds__(256, MINW) void gemm_mfma(
    const int* __restrict__ ids,
    const float* __restrict__ A1, int lda1, int K1,
    const float* __restrict__ A2, int lda2, int K2,
    const float* __restrict__ W1, int ldw1,
    const float* __restrict__ W2, int ldw2,
    const float* __restrict__ bias1, const float* __restrict__ bias2,
    float* __restrict__ C, int ldc, int N) {
  constexpr int LP = BK + 8;       // LDS row pitch in bf16 (+8 pad)
  constexpr int KQ = BK / 4;       // float4 chunks per row
  constexpr int KSUB = BK / 32;    // MFMA K-subtiles per iteration
  constexpr int WAVES_N = (BN >= 64) ? 2 : 1;
  constexpr int WAVES_M = 4 / WAVES_N;
  constexpr int WM = BM / WAVES_M;
  constexpr int FM = WM / 16;
  constexpr int FN = BN / (16 * WAVES_N);  // 32->2, 64->2, 128->4
  constexpr int WN = FN * 16;
  constexpr int ACH = (BM * BK) / (4 * 256);
  constexpr int WCH = (BN * BK) / (4 * 256);
  constexpr int WVN = WTR ? (BK * 8 / 256) : WCH;

  __shared__ unsigned short Al[BM * LP];
  __shared__ unsigned short Wl[BN * LP];

  const int tid = threadIdx.x;
  const int wid = tid >> 6, lane = tid & 63;
  const int nBlock = blockIdx.x * BN;
  const int mBlock = blockIdx.y * BM;
  const int z = blockIdx.z;
  int wm, wn;
  if (WAVES_N == 2) { wm = (wid >> 1) * WM; wn = (wid & 1) * WN; }
  else              { wm = wid * WM;        wn = 0; }

  float4 av[ACH], wv[WVN];

  auto load_tile = [&](int kg) {
    const bool seg1 = kg < K1;
    const float* Wseg = seg1 ? W1 : W2;
    const int ldw = seg1 ? ldw1 : ldw2;
    const int kloc = seg1 ? kg : kg - K1;
#pragma unroll
    for (int i = 0; i < ACH; i++) {
      int c = tid + i * 256;
      int m = c / KQ, kq = (c % KQ) * 4;
      const float* arow;
      if (seg1) {
        if (GATHER) arow = A1 + (size_t)ids[mBlock + m] * lda1;
        else        arow = A1 + (size_t)(mBlock + m) * lda1;
      } else {
        arow = A2 + (size_t)(mBlock + m) * lda2;
      }
      av[i] = *(const float4*)(arow + kloc + kq);
    }
    if (WTR) {
#pragma unroll
      for (int i = 0; i < WVN; i++) {
        int c = tid + i * 256;           // BK k-rows x 8 n-quads
        int row = c >> 3, colq = c & 7;
        wv[i] = *(const float4*)(Wseg + (size_t)(kloc + row) * ldw + nBlock + colq * 4);
      }
    } else {
#pragma unroll
      for (int i = 0; i < WCH; i++) {
        int c = tid + i * 256;
        int n = c / KQ, kq = (c % KQ) * 4;
        wv[i] = *(const float4*)(Wseg + (size_t)(nBlock + n) * ldw + kloc + kq);
      }
    }
  };

  const int KT = K1 + K2;
  const int KS = KT / SPLIT;          // per-split K (multiple of BK; segment-aligned)
  const int kbeg = z * KS;
  const int NS = KS / BK;
  load_tile(kbeg);
  f32x4 acc[FM][FN] = {};

  for (int step = 0; step < NS; ++step) {
    __syncthreads();  // previous iteration's fragment reads done
    // commit regs -> LDS (f32 -> bf16, packed 8B stores)
#pragma unroll
    for (int i = 0; i < ACH; i++) {
      int c = tid + i * 256;
      int m = c / KQ, kq = (c % KQ) * 4;
      *(uint2*)&Al[m * LP + kq] = cvt4(av[i]);
    }
    if (WTR) {
#pragma unroll
      for (int i = 0; i < WVN; i++) {
        int c = tid + i * 256;
        int row = c >> 3, colq = c & 7;
        Wl[(colq * 4 + 0) * LP + row] = cvt1(wv[i].x);
        Wl[(colq * 4 + 1) * LP + row] = cvt1(wv[i].y);
        Wl[(colq * 4 + 2) * LP + row] = cvt1(wv[i].z);
        Wl[(colq * 4 + 3) * LP + row] = cvt1(wv[i].w);
      }
    } else {
#pragma unroll
      for (int i = 0; i < WCH; i++) {
        int c = tid + i * 256;
        int n = c / KQ, kq = (c % KQ) * 4;
        *(uint2*)&Wl[n * LP + kq] = cvt4(wv[i]);
      }
    }
    __syncthreads();

    if (step + 1 < NS) load_tile(kbeg + (step + 1) * BK);  // prefetch

    const int klane = (lane >> 4) << 3;
    const int r = lane & 15;
    short8 af[KSUB][FM], wf[KSUB][FN];
#pragma unroll
    for (int ks = 0; ks < KSUB; ks++) {
#pragma unroll
      for (int f = 0; f < FM; f++)
        af[ks][f] = *(const short8*)&Al[(wm + f * 16 + r) * LP + ks * 32 + klane];
#pragma unroll
      for (int f = 0; f < FN; f++)
        wf[ks][f] = *(const short8*)&Wl[(wn + f * 16 + r) * LP + ks * 32 + klane];
    }
#pragma unroll
    for (int ks = 0; ks < KSUB; ks++)
#pragma unroll
      for (int fm = 0; fm < FM; fm++)
#pragma unroll
        for (int fn = 0; fn < FN; fn++)
          acc[fm][fn] = __builtin_amdgcn_mfma_f32_16x16x32_bf16(
              af[ks][fm], wf[ks][fn], acc[fm][fn], 0, 0, 0);
  }

  // Epilogue. D layout: col = lane&15, row = (lane>>4)*4 + j
  float* Cp = C + (size_t)z * gridDim.y * BM * ldc;
  const int col = lane & 15, rb = (lane >> 4) << 2;
#pragma unroll
  for (int fn = 0; fn < FN; fn++) {
    int n = nBlock + wn + fn * 16 + col;
    float bsum = 0.f;
    if (z == 0) {
      if (bias1) bsum += bias1[n];
      if (bias2) bsum += bias2[n];
    }
#pragma unroll
    for (int fm = 0; fm < FM; fm++) {
#pragma unroll
      for (int j = 0; j < 4; j++) {
        int m = mBlock + wm + fm * 16 + rb + j;
        Cp[(size_t)m * ldc + n] = acc[fm][fn][j] + bsum;
      }
    }
  }
}

// ---------------------------------------------------------------------------
template <int P>
__global__ void lstm_pw(const float* __restrict__ Gp,
                        const float* __restrict__ c_prev,
                        float* __restrict__ h_out,
                        float* __restrict__ c_out) {
  int i4 = blockIdx.x * 256 + threadIdx.x;  // 32768 float4 slots (B*H/4)
  int b = i4 >> 8, j4 = i4 & 255;
  float4 gi{}, gf{}, gg{}, go{};
#pragma unroll
  for (int p = 0; p < P; p++) {
    const float4* g = (const float4*)(Gp + (size_t)p * Bv * 4 * Hv + (size_t)b * 4096);
    float4 a = g[j4], bb = g[256 + j4], c = g[512 + j4], d = g[768 + j4];
    gi.x += a.x; gi.y += a.y; gi.z += a.z; gi.w += a.w;
    gf.x += bb.x; gf.y += bb.y; gf.z += bb.z; gf.w += bb.w;
    gg.x += c.x; gg.y += c.y; gg.z += c.z; gg.w += c.w;
    go.x += d.x; go.y += d.y; go.z += d.z; go.w += d.w;
  }
  float4 c4 = ((const float4*)c_prev)[i4];
  float4 h4, cn4;
  float* gip = &gi.x; float* gfp = &gf.x; float* ggp = &gg.x; float* gop = &go.x;
  float* cp = &c4.x; float* hp = &h4.x; float* cnp = &cn4.x;
#pragma unroll
  for (int u = 0; u < 4; u++) {
    float si = 1.f / (1.f + expf(-gip[u]));
    float sf = 1.f / (1.f + expf(-gfp[u]));
    float so = 1.f / (1.f + expf(-gop[u]));
    float cn = sf * cp[u] + si * tanhf(ggp[u]);
    hp[u] = so * tanhf(cn);
    cnp[u] = cn;
  }
  ((float4*)h_out)[i4] = h4;
  ((float4*)c_out)[i4] = cn4;
}

// ---------------------------------------------------------------------------
// scores[b,s] = <enc[s,b,:], q[b,:]>, q = sum of 4 split-K partials staged in
// LDS once per block (4 waves share b). attn_b term cancels in softmax.
__global__ void scores_k(const float* __restrict__ enc,
                         const float* __restrict__ qp,
                         float* __restrict__ sc) {
  int blk = blockIdx.x;           // B * S/4 = 8192
  int b = blk >> 6, s4 = blk & 63;
  int t = threadIdx.x;
  __shared__ float qs[1024];
  {
    const float4* q0 = (const float4*)(qp + (size_t)b * Hv);
    const float4* q1 = (const float4*)(qp + 1 * Bv * Hv + (size_t)b * Hv);
    const float4* q2 = (const float4*)(qp + 2 * Bv * Hv + (size_t)b * Hv);
    const float4* q3 = (const float4*)(qp + 3 * Bv * Hv + (size_t)b * Hv);
    float4 a = q0[t], bq = q1[t], c = q2[t], d = q3[t];
    float4 s;
    s.x = a.x + bq.x + c.x + d.x; s.y = a.y + bq.y + c.y + d.y;
    s.z = a.z + bq.z + c.z + d.z; s.w = a.w + bq.w + c.w + d.w;
    ((float4*)qs)[t] = s;
  }
  __syncthreads();
  int wid = t >> 6, lane = t & 63;
  int s = s4 * 4 + wid;
  const float4* e4 = (const float4*)(enc + ((size_t)s * Bv + b) * Hv);
  const float4* q4 = (const float4*)qs;
  float sum = 0.f;
#pragma unroll
  for (int i = 0; i < 4; i++) {
    int idx = lane + i * 64;
    float4 e = e4[idx], qq = q4[idx];
    sum += e.x * qq.x + e.y * qq.y + e.z * qq.z + e.w * qq.w;
  }
#pragma unroll
  for (int o = 32; o; o >>= 1) sum += __shfl_xor(sum, o);
  if (lane == 0) sc[(size_t)b * Sv + s] = sum;
}

// ---------------------------------------------------------------------------
// Per block (b, h-quarter): softmax over sc[b,:] (recomputed redundantly,
// cheap) then ctx[b, hc:hc+256] = sum_s attn[s] * enc[s,b,hc:hc+256].
__global__ void context_k(const float* __restrict__ sc_in,
                          const float* __restrict__ enc,
                          float* __restrict__ ctx) {
  int blk = blockIdx.x;                 // B * 4 = 512
  int b = blk >> 2, hc = (blk & 3) * 256;
  int t = threadIdx.x, lane = t & 63;
  __shared__ float a[256];
  __shared__ float redm[4], reds[4];
  float v = sc_in[(size_t)b * Sv + t];
  float m = v;
#pragma unroll
  for (int o = 32; o; o >>= 1) m = fmaxf(m, __shfl_xor(m, o));
  if (lane == 0) redm[t >> 6] = m;
  __syncthreads();
  m = fmaxf(fmaxf(redm[0], redm[1]), fmaxf(redm[2], redm[3]));
  float e = expf(v - m);
  float ssum = e;
#pragma unroll
  for (int o = 32; o; o >>= 1) ssum += __shfl_xor(ssum, o);
  if (lane == 0) reds[t >> 6] = ssum;
  __syncthreads();
  ssum = (reds[0] + reds[1]) + (reds[2] + reds[3]);
  a[t] = e / ssum;
  __syncthreads();

  float acc = 0.f;
  const float* ebase = enc + (size_t)b * Hv + hc + t;
#pragma unroll 8
  for (int s = 0; s < Sv; s++)
    acc += a[s] * ebase[(size_t)s * Bv * Hv];
  ctx[(size_t)b * Hv + hc + t] = acc;
}

// ---------------------------------------------------------------------------
__global__ void finish_cat(const float* __restrict__ catp,
                           float* __restrict__ cat) {
  int i4 = blockIdx.x * 256 + threadIdx.x;  // 32768 float4 slots
  constexpr int ST = Bv * Hv / 4;
  const float4* p = (const float4*)catp;
  float4 a = p[i4], b = p[ST + i4], c = p[2 * ST + i4], d = p[3 * ST + i4];
  float4 r;
  r.x = tanhf(a.x + b.x + c.x + d.x);
  r.y = tanhf(a.y + b.y + c.y + d.y);
  r.z = tanhf(a.z + b.z + c.z + d.z);
  r.w = tanhf(a.w + b.w + c.w + d.w);
  ((float4*)cat)[i4] = r;
}

// ---------------------------------------------------------------------------
extern "C" void kernel_launch(void* const* d_in, const int* in_sizes, int n_in,
                              void* d_out, int out_size, void* d_ws,
                              size_t ws_size, hipStream_t stream) {
  const int*   ids      = (const int*)d_in[0];
  const float* h0       = (const float*)d_in[1];
  const float* c0       = (const float*)d_in[2];
  const float* enc      = (const float*)d_in[3];
  const float* emb      = (const float*)d_in[4];
  const float* w_ih0    = (const float*)d_in[5];
  const float* w_hh0    = (const float*)d_in[6];
  const float* b_ih0    = (const float*)d_in[7];
  const float* b_hh0    = (const float*)d_in[8];
  const float* w_ih1    = (const float*)d_in[9];
  const float* w_hh1    = (const float*)d_in[10];
  const float* b_ih1    = (const float*)d_in[11];
  const float* b_hh1    = (const float*)d_in[12];
  const float* attn_w   = (const float*)d_in[13];
  const float* attn_b   = (const float*)d_in[14];  // cancels in softmax
  const float* concat_w = (const float*)d_in[15];
  const float* concat_b = (const float*)d_in[16];
  const float* out_w    = (const float*)d_in[17];
  const float* out_b    = (const float*)d_in[18];
  (void)attn_b;

  float* logits = (float*)d_out;                  // [128, 32000]
  float* hout   = logits + (size_t)Bv * Vv;       // [2, 128, 1024]
  float* cout   = hout + 2 * Bv * Hv;             // [2, 128, 1024]

  float* ws   = (float*)d_ws;
  float* G0p  = ws;                       // 3 * 524288
  float* G1p  = G0p + 3 * 524288;         // 4 * 524288
  float* qp   = G1p + 4 * (size_t)524288; // 4 * 131072
  float* catp = qp + 4 * 131072;          // 4 * 131072
  float* cat  = catp + 4 * 131072;        // 131072
  float* ctx  = cat + 131072;             // 131072
  float* sc   = ctx + 131072;             // 32768

  const float* h_b = hout + Bv * Hv;  // layer-1 h (rnn_out)

  // 1. LSTM layer 0 gates: K = 512(emb,gathered) + 1024(h0), 3-way split-K
  gemm_mfma<64, 32, 64, 3, 0, 1, 4><<<dim3(128, 2, 3), 256, 0, stream>>>(
      ids, emb, Ev, Ev, h0, Hv, Hv, w_ih0, Ev, w_hh0, Hv, b_ih0, b_hh0,
      G0p, 4 * Hv, 4 * Hv);
  // 2. LSTM layer 0 pointwise (sums 3 partials); h -> hout[0]
  lstm_pw<3><<<128, 256, 0, stream>>>(G0p, c0, hout, cout);
  // 3. LSTM layer 1 gates: K = 1024(h_layer0) + 1024(h0[1]), 4-way split-K
  gemm_mfma<64, 32, 64, 4, 0, 0, 4><<<dim3(128, 2, 4), 256, 0, stream>>>(
      nullptr, hout, Hv, Hv, h0 + Bv * Hv, Hv, Hv, w_ih1, Hv, w_hh1, Hv,
      b_ih1, b_hh1, G1p, 4 * Hv, 4 * Hv);
  // 4. LSTM layer 1 pointwise (sums 4 partials)
  lstm_pw<4><<<128, 256, 0, stream>>>(G1p, c0 + Bv * Hv, hout + Bv * Hv,
                                      cout + Bv * Hv);
  // 5. q = rnn @ attn_w (transposed in staging), 4-way split-K
  gemm_mfma<64, 32, 64, 4, 1, 0, 4><<<dim3(32, 2, 4), 256, 0, stream>>>(
      nullptr, h_b, Hv, Hv, nullptr, 0, 0, attn_w, Hv,
      nullptr, 0, nullptr, nullptr, qp, Hv, Hv);
  // 6. scores (sums q partials via LDS once per block)
  scores_k<<<8192, 256, 0, stream>>>(enc, qp, sc);
  // 7. softmax (redundant per block) + context
  context_k<<<512, 256, 0, stream>>>(sc, enc, ctx);
  // 8. concat gates: K = 1024(rnn) + 1024(ctx), 4-way split-K
  gemm_mfma<64, 32, 64, 4, 0, 0, 4><<<dim3(32, 2, 4), 256, 0, stream>>>(
      nullptr, h_b, Hv, Hv, ctx, Hv, Hv, concat_w, 2 * Hv,
      concat_w + Hv, 2 * Hv, concat_b, nullptr, catp, Hv, Hv);
  // 9. cat = tanh(sum of partials)
  finish_cat<<<128, 256, 0, stream>>>(catp, cat);
  // 10. logits: BM=128/BN=128/BK=64, grid (250,1) -> ONE m-level:
  //     out_w (131 MB) read exactly once (no L3 duplicate pass); ~1 block/CU
  //     with 16x16B loads in flight/thread = 64KB/CU outstanding (memcpy-
  //     like depth, HBM-saturating). A (cat, 512KB) served from L2/L3.
  gemm_mfma<128, 128, 64, 1, 0, 0, 1><<<dim3(250, 1, 1), 256, 0, stream>>>(
      nullptr, cat, Hv, Hv, nullptr, 0, 0, out_w, Hv, nullptr, 0,
      out_b, nullptr, logits, Vv, Vv);
}